// Round 4
// baseline (610.363 us; speedup 1.0000x reference)
//
#include <hip/hip_runtime.h>
#include <stdint.h>

// dx/dt = F - B*x - r * rowsum(x * (A@x))  broadcast over DIM
// A: 10000x10000 f32 streamed once (400MB -> ~63.5us HBM floor).
// A@x via bf16 MFMA 16x16x32 (absmax 4.0 vs threshold 20.64 — verified R1).
//
// R8: MEASUREMENT ROUND. Four structural theories in a row failed flat
// (R5 reg-direct +63, R6 counted-vmcnt +17, R7 4KB-bursts +24, all vs R4
// 524). The gemm's true duration has never been visible: it sits just
// below the top-5 cutoff (fills ~243-251us) every round, and R5's cutoff
// (<242.5) contradicts its +63 total -> the "gemm=240us" decomposition
// is unverified. This round: R4's EXACT best-known gemm, K-loop run
// TWICE (re-reads A, acc doubles, epilogue scales by 0.5f — exact pow2,
// absmax unchanged). gemm duration doubles -> lands in top-5 -> full
// counter row (dur/hbm_gbps/FETCH/MfmaUtil/VALUBusy/Occupancy/bankconf).
// Pre-committed readout: [A] ~480us @1.7TB/s low-util -> pattern-limited;
// [B] VALUBusy>70 -> VALU-bound staging; [C] ~200-300us @2.7-4TB/s ->
// gemm fast, total is overhead-dominated; [D] absent from top-5 ->
// gemm<122us, overhead story confirmed. Predict total ~630-780us.

#define N_ROWS 10000
#define DIM 64
#define KTILE 32
#define NKT 320      // K padded to 10240: 320 tiles of 32; B zero-filled past 10000
#define CHUNK_K 256  // K-chunk staged per block iteration (8 tiles)
#define CHUNKS_PER_Y 20
#define F_CONST 1.0f
#define B_CONST 0.1f
#define R_CONST 0.01f

#define SACC_OFF_BYTES 1310720  // packed B ends at 320*4*64*16 = 1310720

typedef __attribute__((ext_vector_type(8))) short s16x8;   // 8 bf16 (MFMA A/B frag)
typedef __attribute__((ext_vector_type(4))) float f32x4;   // MFMA C/D frag
typedef __attribute__((ext_vector_type(4))) uint32_t u32x4;
typedef __attribute__((ext_vector_type(2))) uint32_t u32x2;

// round-to-nearest f32 -> bf16, packed pair into one u32
__device__ __forceinline__ uint32_t pack_bf16(float a, float b) {
    uint32_t ua = __builtin_bit_cast(uint32_t, a);
    uint32_t ub = __builtin_bit_cast(uint32_t, b);
    ua += 0x7FFFu + ((ua >> 16) & 1u);
    ub += 0x7FFFu + ((ub >> 16) & 1u);
    return (ua >> 16) | (ub & 0xFFFF0000u);
}

// Pack x into per-lane-contiguous MFMA B fragments (bf16), zero-padded past K=10000.
// Fragment id = t*4 + c, t in [0,320). Lane L holds B[k=t*32+(L>>4)*8+j][col=c*16+(L&15)].
// Also zeroes the per-row dot accumulator (ws is re-poisoned 0xAA every call).
__global__ __launch_bounds__(256) void pack_x_kernel(const float* __restrict__ x,
                                                     uint32_t* __restrict__ ws,
                                                     float* __restrict__ sacc) {
    int id = blockIdx.x * 256 + threadIdx.x;  // 0 .. 81919
    if (id < N_ROWS) sacc[id] = 0.0f;
    int frag = id >> 6;
    int L = id & 63;
    int t = frag >> 2;
    int c = frag & 3;
    int k0 = t * KTILE + (L >> 4) * 8;
    int col = c * 16 + (L & 15);
    float v[8];
#pragma unroll
    for (int j = 0; j < 8; ++j) {
        int k = k0 + j;
        v[j] = (k < N_ROWS) ? x[k * DIM + col] : 0.0f;
    }
    u32x4 p;
    p.x = pack_bf16(v[0], v[1]);
    p.y = pack_bf16(v[2], v[3]);
    p.z = pack_bf16(v[4], v[5]);
    p.w = pack_bf16(v[6], v[7]);
    ((u32x4*)ws)[id] = p;
}

// R4's gemm verbatim, except the whole chunk pipeline runs twice (PASSES=2)
// and the epilogue scales by 1/PASSES. blockIdx.x = row tile (16 rows),
// blockIdx.y = K half (20 chunks of 256 each). Per chunk: 4 waves stage
// 16 rows x 256 k of A (1KB contiguous per wave-instr), bf16-pack, write
// to XOR-swizzled LDS; each wave MFMAs 2 of the 8 K-tiles. Double-buffered,
// 1 barrier/chunk.
__global__ __launch_bounds__(256, 4) void gemm_dot_kernel(
    const float* __restrict__ A, const float* __restrict__ x,
    const uint32_t* __restrict__ ws, float* __restrict__ sacc) {
    // bf16 tile [16 rows][256 k], row stride 512B = 32 16B-units.
    // Swizzle: 16B-unit u of row r stored at u ^ (r & 7).
    __shared__ __align__(16) unsigned short lds[2][16 * CHUNK_K];

    int tid = threadIdx.x;
    int w = tid >> 6;       // wave 0..3
    int L = tid & 63;       // lane
    int quad = L >> 4;      // 0..3
    int m = L & 15;         // A-row-in-tile / B col-in-16
    int rbase = blockIdx.x * 16;
    int c0 = blockIdx.y * CHUNKS_PER_Y;
    int c1 = c0 + CHUNKS_PER_Y;
    const float* Ab = A + (size_t)rbase * N_ROWS;

    f32x4 acc[4] = {{0.f, 0.f, 0.f, 0.f},
                    {0.f, 0.f, 0.f, 0.f},
                    {0.f, 0.f, 0.f, 0.f},
                    {0.f, 0.f, 0.f, 0.f}};

    for (int pass = 0; pass < 2; ++pass) {
        // ---- prologue: stage chunk c0 into buf 0 ----
        {
            f32x4 ld[4];
#pragma unroll
            for (int i = 0; i < 4; ++i) {
                int row = i * 4 + w;
                int kg = c0 * CHUNK_K + L * 4;
                int ks = (kg <= N_ROWS - 4) ? kg : (N_ROWS - 4);  // finite pad (B=0 there)
                ld[i] = __builtin_nontemporal_load((const f32x4*)(Ab + (size_t)row * N_ROWS + ks));
            }
#pragma unroll
            for (int i = 0; i < 4; ++i) {
                int row = i * 4 + w;
                int unit = (L >> 1) ^ (row & 7);
                u32x2 pk;
                pk.x = pack_bf16(ld[i].x, ld[i].y);
                pk.y = pack_bf16(ld[i].z, ld[i].w);
                *(u32x2*)((char*)lds[0] + row * 512 + (unit << 4) + ((L & 1) << 3)) = pk;
            }
        }
        __syncthreads();

        int p = 0;
        for (int c = c0; c < c1; ++c) {
            // issue next chunk's global loads first (overlap with MFMA below)
            f32x4 ld[4];
            bool more = (c + 1 < c1);
            if (more) {
#pragma unroll
                for (int i = 0; i < 4; ++i) {
                    int row = i * 4 + w;
                    int kg = (c + 1) * CHUNK_K + L * 4;
                    int ks = (kg <= N_ROWS - 4) ? kg : (N_ROWS - 4);
                    ld[i] = __builtin_nontemporal_load((const f32x4*)(Ab + (size_t)row * N_ROWS + ks));
                }
            }

            // MFMA on buffer p: wave w handles tiles w and w+4 of this chunk
#pragma unroll
            for (int u = 0; u < 2; ++u) {
                int tt = w + 4 * u;
                int T = c * 8 + tt;
                int unit = (tt * 4 + quad) ^ (m & 7);
                s16x8 afrag = *(const s16x8*)((const char*)lds[p] + m * 512 + (unit << 4));
                const u32x4* pb = (const u32x4*)ws + (size_t)T * 256 + L;
#pragma unroll
                for (int cc = 0; cc < 4; ++cc) {
                    s16x8 bfrag = __builtin_bit_cast(s16x8, pb[cc * 64]);
                    acc[cc] = __builtin_amdgcn_mfma_f32_16x16x32_bf16(afrag, bfrag, acc[cc], 0, 0, 0);
                }
            }

            if (more) {
#pragma unroll
                for (int i = 0; i < 4; ++i) {
                    int row = i * 4 + w;
                    int unit = (L >> 1) ^ (row & 7);
                    u32x2 pk;
                    pk.x = pack_bf16(ld[i].x, ld[i].y);
                    pk.y = pack_bf16(ld[i].z, ld[i].w);
                    *(u32x2*)((char*)lds[p ^ 1] + row * 512 + (unit << 4) + ((L & 1) << 3)) = pk;
                }
            }
            __syncthreads();
            p ^= 1;
        }
        // all reads of both buffers complete (loop ends with __syncthreads),
        // safe to re-stage buf 0 at the top of the next pass
    }

    // Per-wave epilogue. C/D layout: acc[cc][r] = Ax_partial[row=quad*4+r][col=cc*16+m].
    // acc holds 2x the partials (two identical passes) -> scale by 0.5f (exact).
    float pr[4];
#pragma unroll
    for (int r = 0; r < 4; ++r) {
        int grow = rbase + quad * 4 + r;
        const float* xr = x + (size_t)grow * DIM + m;
        pr[r] = acc[0][r] * xr[0] + acc[1][r] * xr[16] +
                acc[2][r] * xr[32] + acc[3][r] * xr[48];
        pr[r] *= 0.5f;
        pr[r] += __shfl_xor(pr[r], 1);
        pr[r] += __shfl_xor(pr[r], 2);
        pr[r] += __shfl_xor(pr[r], 4);
        pr[r] += __shfl_xor(pr[r], 8);
    }
    if (m == 0) {
#pragma unroll
        for (int r = 0; r < 4; ++r)
            atomicAdd(&sacc[rbase + quad * 4 + r], pr[r]);
    }
}

__global__ __launch_bounds__(256) void finalize_kernel(const float* __restrict__ x,
                                                       const float* __restrict__ sacc,
                                                       float* __restrict__ out) {
    int id = blockIdx.x * 256 + threadIdx.x;  // 0 .. 159999 (f32x4 units)
    f32x4 xv = ((const f32x4*)x)[id];
    float s = R_CONST * sacc[id >> 4];
    f32x4 o;
    o.x = F_CONST - B_CONST * xv.x - s;
    o.y = F_CONST - B_CONST * xv.y - s;
    o.z = F_CONST - B_CONST * xv.z - s;
    o.w = F_CONST - B_CONST * xv.w - s;
    ((f32x4*)out)[id] = o;
}

extern "C" void kernel_launch(void* const* d_in, const int* in_sizes, int n_in,
                              void* d_out, int out_size, void* d_ws, size_t ws_size,
                              hipStream_t stream) {
    // inputs: t (1, unused), x (10000*64 f32), A (10000*10000 f32)
    const float* x = (const float*)d_in[1];
    const float* A = (const float*)d_in[2];
    float* out = (float*)d_out;
    uint32_t* ws = (uint32_t*)d_ws;  // [0, 1.31MB): packed bf16 x fragments (320 tiles)
    float* sacc = (float*)((char*)d_ws + SACC_OFF_BYTES);  // 40KB row-dot acc

    pack_x_kernel<<<320, 256, 0, stream>>>(x, ws, sacc);
    gemm_dot_kernel<<<dim3(625, 2), 256, 0, stream>>>(A, x, ws, sacc);
    finalize_kernel<<<625, 256, 0, stream>>>(x, sacc, out);
}